// Round 1
// 689.990 us; speedup vs baseline: 1.0102x; 1.0102x over previous
//
#include <hip/hip_runtime.h>

#define BATCH 16384
#define KDIM  3072
#define NDIM  3072

typedef __bf16 bf16;
typedef bf16  bf16x8  __attribute__((ext_vector_type(8)));
typedef float f32x16  __attribute__((ext_vector_type(16)));

// async global->LDS, 16B per lane. HW dest = wave-uniform base + lane*16.
__device__ __forceinline__ void g2l16(const bf16* g, bf16* l) {
    __builtin_amdgcn_global_load_lds(
        (__attribute__((address_space(1))) unsigned int*)g,
        (__attribute__((address_space(3))) unsigned int*)l,
        16, 0, 0);
}

// ---- prep 1: fp32 inputs -> bf16, 8 elems/thread ----
__global__ __launch_bounds__(256) void cvt_a_kernel(const float* __restrict__ in,
                                                    bf16* __restrict__ out) {
    const long idx = (long)blockIdx.x * 256 + threadIdx.x;
    const float4* in4 = (const float4*)in;
    float4 a = in4[idx * 2];
    float4 b = in4[idx * 2 + 1];
    bf16x8 o;
    o[0] = (bf16)a.x; o[1] = (bf16)a.y; o[2] = (bf16)a.z; o[3] = (bf16)a.w;
    o[4] = (bf16)b.x; o[5] = (bf16)b.y; o[6] = (bf16)b.z; o[7] = (bf16)b.w;
    ((bf16x8*)out)[idx] = o;
}

// ---- prep 2: Weff_t[u][i] = bf16(w[i][u] * mask[u][i]) via LDS transpose ----
__global__ __launch_bounds__(256) void weff_kernel(const float* __restrict__ w,
                                                   const int* __restrict__ mask,
                                                   bf16* __restrict__ wt) {
    __shared__ float tile[32][33];
    const int i0 = blockIdx.x * 32;
    const int u0 = blockIdx.y * 32;
    const int tx = threadIdx.x, ty = threadIdx.y;
#pragma unroll
    for (int r = 0; r < 4; r++)
        tile[ty + 8 * r][tx] = w[(long)(i0 + ty + 8 * r) * NDIM + u0 + tx];
    __syncthreads();
#pragma unroll
    for (int r = 0; r < 4; r++) {
        int u = u0 + ty + 8 * r;
        int i = i0 + tx;
        float v = tile[tx][ty + 8 * r] * (float)mask[(long)u * KDIM + i];
        wt[(long)u * KDIM + i] = (bf16)v;
    }
}

// ---- main GEMM: C[m][n] = A[m][k] * Bt[n][k] + bias[n] ----
// 256x256 tile, BK=64, 8 waves (2M x 4N, each wave 128x64 via 4x2 grid of
// mfma_f32_32x32x16). LDS: 2 buffers x (A 32KB + B 32KB) = 128KB, 1 block/CU.
// Counted-vmcnt pipeline (T4): tile i+2 staged right after compute of tile i;
// main loop waits s_waitcnt vmcnt(8) (tile i+1's 8 loads stay in flight) —
// never drains to 0 until the epilogue.
// T2 swizzle (rule 21, both-sides): LDS rows are 128B (8 x 16B chunks); reads
// use chunk c ^ (row&7); global_load_lds writes linearly, so the staging
// *source* chunk is pre-swizzled: sc = (tid&7) ^ ((tid>>3)&7). Each group of
// 8 lanes still reads one contiguous 128B global segment (coalesced).
__global__ __launch_bounds__(512, 2) void gemm_kernel(const bf16* __restrict__ A,   // [BATCH][KDIM]
                                                      const bf16* __restrict__ Bt,  // [NDIM][KDIM]
                                                      const float* __restrict__ bias,
                                                      float* __restrict__ C) {      // [BATCH][NDIM]
    __shared__ __align__(16) bf16 lds[2 * 32768];  // 128 KiB

    const int tid  = threadIdx.x;
    const int lane = tid & 63;
    const int wv   = tid >> 6;
    const int rl   = lane & 31;
    const int kb   = lane >> 5;
    const int sx   = rl & 7;  // read-side swizzle for this lane's rows

    // T1: XCD swizzle. 768 blocks, 8 XCDs -> 96 contiguous blocks (8 A-panels)
    // per XCD. 768 % 8 == 0 -> bijective.
    const int lid = blockIdx.y * gridDim.x + blockIdx.x;  // grid = (12, 64)
    const int sid = (lid & 7) * 96 + (lid >> 3);
    const long m0 = (long)(sid / 12) * 256;
    const long n0 = (long)(sid % 12) * 256;

    const int waveM = (wv >> 2) * 128;
    const int waveN = (wv & 3) * 64;

    // staging: row = 64j + tid>>3, source chunk pre-swizzled
    const int srow = tid >> 3;
    const int sc   = (tid & 7) ^ (srow & 7);
    const bf16* gA = A  + (m0 + srow) * KDIM + sc * 8;
    const bf16* gB = Bt + (n0 + srow) * KDIM + sc * 8;
    bf16* const dA = &lds[tid * 8];
    bf16* const dB = &lds[16384 + tid * 8];

    // fragment row bases (elem units). Read chunk = ((ks*2)|kb) ^ sx.
    const int aBase = (waveM + rl) * 64;
    const int bBase = 16384 + (waveN + rl) * 64;

    f32x16 acc[4][2] = {};

    auto STAGE = [&](int p, int kt) {
        const long ko = (long)kt * 64;
        bf16* da = dA + p * 32768;
        bf16* db = dB + p * 32768;
#pragma unroll
        for (int j = 0; j < 4; ++j) g2l16(gA + (long)(64 * j) * KDIM + ko, da + j * 4096);
#pragma unroll
        for (int j = 0; j < 4; ++j) g2l16(gB + (long)(64 * j) * KDIM + ko, db + j * 4096);
    };

    // register-double-buffered fragments: ks+1 ds_reads issue under ks MFMAs.
    auto COMPUTE = [&](const bf16* bp) {
        bf16x8 af[2][4], bfr[2][2];
        {
            const int c = kb ^ sx;  // ks = 0
#pragma unroll
            for (int mi = 0; mi < 4; ++mi)
                af[0][mi] = *(const bf16x8*)(bp + aBase + mi * 2048 + c * 8);
#pragma unroll
            for (int ni = 0; ni < 2; ++ni)
                bfr[0][ni] = *(const bf16x8*)(bp + bBase + ni * 2048 + c * 8);
        }
#pragma unroll
        for (int ks = 0; ks < 4; ++ks) {
            const int cur = ks & 1, nxt = cur ^ 1;  // static under unroll
            if (ks < 3) {
                const int c = ((ks + 1) * 2 + kb) ^ sx;
#pragma unroll
                for (int mi = 0; mi < 4; ++mi)
                    af[nxt][mi] = *(const bf16x8*)(bp + aBase + mi * 2048 + c * 8);
#pragma unroll
                for (int ni = 0; ni < 2; ++ni)
                    bfr[nxt][ni] = *(const bf16x8*)(bp + bBase + ni * 2048 + c * 8);
            }
            __builtin_amdgcn_s_setprio(1);  // T5
#pragma unroll
            for (int mi = 0; mi < 4; ++mi)
#pragma unroll
                for (int ni = 0; ni < 2; ++ni)
                    acc[mi][ni] = __builtin_amdgcn_mfma_f32_32x32x16_bf16(
                        af[cur][mi], bfr[cur][ni], acc[mi][ni], 0, 0, 0);
            __builtin_amdgcn_s_setprio(0);
        }
    };

    const int NT = KDIM / 64;  // 48
    STAGE(0, 0);
    STAGE(1, 1);

#pragma unroll 2
    for (int i = 0; i < NT - 2; ++i) {
        const int p = i & 1;
        // tile i's 8 loads done; tile i+1's 8 stay in flight (never vmcnt(0))
        asm volatile("s_waitcnt vmcnt(8)" ::: "memory");
        __builtin_amdgcn_s_barrier();
        asm volatile("" ::: "memory");  // no ds_read hoisted above barrier
        COMPUTE(&lds[p * 32768]);
        // own frag reads drained -> all waves past barrier -> safe to overwrite
        asm volatile("s_waitcnt lgkmcnt(0)" ::: "memory");
        __builtin_amdgcn_s_barrier();
        asm volatile("" ::: "memory");
        STAGE(p, i + 2);
    }
    // i = NT-2 (p = 0): no more staging, still only wait to depth 8
    asm volatile("s_waitcnt vmcnt(8)" ::: "memory");
    __builtin_amdgcn_s_barrier();
    asm volatile("" ::: "memory");
    COMPUTE(&lds[0]);
    // i = NT-1 (p = 1): final tile, drain
    asm volatile("s_waitcnt vmcnt(0)" ::: "memory");
    __builtin_amdgcn_s_barrier();
    asm volatile("" ::: "memory");
    COMPUTE(&lds[32768]);

    // epilogue: C/D layout col=lane&31, row=(reg&3)+8*(reg>>2)+4*(lane>>5)
#pragma unroll
    for (int ni = 0; ni < 2; ++ni) {
        const long col = n0 + waveN + ni * 32 + rl;
        const float bv = bias[col];
#pragma unroll
        for (int mi = 0; mi < 4; ++mi) {
            const long rbase = m0 + waveM + mi * 32 + 4 * kb;
#pragma unroll
            for (int g = 0; g < 4; ++g)
#pragma unroll
                for (int t = 0; t < 4; ++t)
                    C[(rbase + 8 * g + t) * NDIM + col] = acc[mi][ni][4 * g + t] + bv;
        }
    }
}

// ---- fallback (only if ws_size too small): naive fp32 masked GEMM ----
__global__ __launch_bounds__(256) void naive_kernel(const float* __restrict__ x,
                                                    const float* __restrict__ w,
                                                    const float* __restrict__ bias,
                                                    const int* __restrict__ mask,
                                                    float* __restrict__ out) {
    const long idx = (long)blockIdx.x * 256 + threadIdx.x;
    const long bi = idx / NDIM;
    const int u = (int)(idx % NDIM);
    float s = 0.f;
    for (int k = 0; k < KDIM; k++)
        s += x[bi * KDIM + k] * w[(long)k * NDIM + u] * (float)mask[(long)u * KDIM + k];
    out[idx] = s + bias[u];
}

extern "C" void kernel_launch(void* const* d_in, const int* in_sizes, int n_in,
                              void* d_out, int out_size, void* d_ws, size_t ws_size,
                              hipStream_t stream) {
    const float* x    = (const float*)d_in[0];  // [16384, 3072] fp32
    const float* w    = (const float*)d_in[1];  // [3072, 3072] fp32
    const float* bias = (const float*)d_in[2];  // [3072] fp32
    const int*   mask = (const int*)d_in[3];    // [3072, 3072] int32
    float* out = (float*)d_out;                 // [16384, 3072] fp32

    const size_t needA = (size_t)BATCH * KDIM * sizeof(bf16);  // ~100.7 MB
    const size_t needW = (size_t)NDIM * KDIM * sizeof(bf16);   // ~18.9 MB

    if (ws_size < needA + needW) {
        const long total = (long)BATCH * NDIM;
        naive_kernel<<<(int)(total / 256), 256, 0, stream>>>(x, w, bias, mask, out);
        return;
    }

    bf16* Abf = (bf16*)d_ws;
    bf16* Wt  = (bf16*)((char*)d_ws + needA);

    cvt_a_kernel<<<(BATCH * (KDIM / 8)) / 256, 256, 0, stream>>>(x, Abf);
    weff_kernel<<<dim3(KDIM / 32, NDIM / 32), dim3(32, 8), 0, stream>>>(w, mask, Wt);
    gemm_kernel<<<dim3(NDIM / 256, BATCH / 256), 512, 0, stream>>>(Abf, Wt, bias, out);
}

// Round 3
// 684.392 us; speedup vs baseline: 1.0185x; 1.0082x over previous
//
#include <hip/hip_runtime.h>

#define BATCH 16384
#define KDIM  3072
#define NDIM  3072

typedef __bf16 bf16;
typedef bf16  bf16x8  __attribute__((ext_vector_type(8)));
typedef float f32x16  __attribute__((ext_vector_type(16)));

// async global->LDS, 16B per lane. HW dest = wave-uniform base + lane*16.
__device__ __forceinline__ void g2l16(const bf16* g, bf16* l) {
    __builtin_amdgcn_global_load_lds(
        (__attribute__((address_space(1))) unsigned int*)g,
        (__attribute__((address_space(3))) unsigned int*)l,
        16, 0, 0);
}

// ---- prep 1: fp32 inputs -> bf16, 8 elems/thread ----
__global__ __launch_bounds__(256) void cvt_a_kernel(const float* __restrict__ in,
                                                    bf16* __restrict__ out) {
    const long idx = (long)blockIdx.x * 256 + threadIdx.x;
    const float4* in4 = (const float4*)in;
    float4 a = in4[idx * 2];
    float4 b = in4[idx * 2 + 1];
    bf16x8 o;
    o[0] = (bf16)a.x; o[1] = (bf16)a.y; o[2] = (bf16)a.z; o[3] = (bf16)a.w;
    o[4] = (bf16)b.x; o[5] = (bf16)b.y; o[6] = (bf16)b.z; o[7] = (bf16)b.w;
    ((bf16x8*)out)[idx] = o;
}

// ---- prep 2: Weff_t[u][i] = bf16(w[i][u] * mask[u][i]) via LDS transpose ----
__global__ __launch_bounds__(256) void weff_kernel(const float* __restrict__ w,
                                                   const int* __restrict__ mask,
                                                   bf16* __restrict__ wt) {
    __shared__ float tile[32][33];
    const int i0 = blockIdx.x * 32;
    const int u0 = blockIdx.y * 32;
    const int tx = threadIdx.x, ty = threadIdx.y;
#pragma unroll
    for (int r = 0; r < 4; r++)
        tile[ty + 8 * r][tx] = w[(long)(i0 + ty + 8 * r) * NDIM + u0 + tx];
    __syncthreads();
#pragma unroll
    for (int r = 0; r < 4; r++) {
        int u = u0 + ty + 8 * r;
        int i = i0 + tx;
        float v = tile[tx][ty + 8 * r] * (float)mask[(long)u * KDIM + i];
        wt[(long)u * KDIM + i] = (bf16)v;
    }
}

// ---- main GEMM: C[m][n] = A[m][k] * Bt[n][k] + bias[n] ----
// 256x256 tile, BK=64, 8 waves (2M x 4N), per-wave 128x64 via 4x2 grid of
// mfma_f32_32x32x16. LDS 128 KiB: 2 buffers x (A 32KB + B 32KB), K-HALF-major
// layout: [kh][row][32 K'] with 64B rows, so staging units (A-kh / B-kh,
// 2 gloads each) align with consumption order.
// 8-phase-style schedule (T3+T4+T5): 4 phases per K-tile, phase ks =
//   { 6 ds_read (ks-subtile) ; 2 global_load_lds (one unit of tile t+1) ;
//     barrier ; lgkmcnt(0) ; sched_barrier ; setprio(1) 8xMFMA setprio(0) ;
//     [vmcnt(4) at kh boundary] ; barrier }
// vmcnt never drains below 4 in the main loop. Swizzle (T2, rule 21 both
// sides): source chunk sc = c ^ (row&3); read chunk = c0 ^ (rl&3).
// Hazards: buf q written only after the closing barrier of the tile that read
// it; kh arrival enforced by wave-symmetric vmcnt(4)+barrier before first use.

#define STAGE_UNIT(Q, KT, KS) do {                                              \
    const long ko_ = (long)(KT) * 64 + ((KS) >> 1) * 32;                        \
    const bf16* gs_ = (((KS) & 1) == 0) ? gA : gB;                              \
    bf16* ds_ = &lds[(Q) * 32768 + ((((KS) & 1) == 0) ? 0 : 16384)              \
                     + ((KS) >> 1) * 8192 + tid * 8];                           \
    g2l16(gs_ + ko_, ds_);                                                      \
    g2l16(gs_ + ko_ + (long)128 * KDIM, ds_ + 4096);                            \
} while (0)

#define PHASE(KS, P, DOSTAGE, KT, VM) do {                                      \
    asm volatile("" ::: "memory"); /* keep reads below previous barrier */      \
    const bf16* bp_ = &lds[(P) * 32768];                                        \
    const int cOff_ = ((KS) >> 1) * 8192 + (((((KS) & 1) * 2) + kb) ^ sx3) * 8; \
    bf16x8 a0_ = *(const bf16x8*)(bp_ + aOff0 + cOff_);                         \
    bf16x8 a1_ = *(const bf16x8*)(bp_ + aOff1 + cOff_);                         \
    bf16x8 a2_ = *(const bf16x8*)(bp_ + aOff2 + cOff_);                         \
    bf16x8 a3_ = *(const bf16x8*)(bp_ + aOff3 + cOff_);                         \
    bf16x8 b0_ = *(const bf16x8*)(bp_ + bOff0 + cOff_);                         \
    bf16x8 b1_ = *(const bf16x8*)(bp_ + bOff1 + cOff_);                         \
    if (DOSTAGE) { STAGE_UNIT((P) ^ 1, KT, KS); }                               \
    asm volatile("" ::: "memory"); /* keep reads/stage above barrier */         \
    __builtin_amdgcn_s_barrier();                                               \
    asm volatile("s_waitcnt lgkmcnt(0)" ::: "memory");                          \
    __builtin_amdgcn_sched_barrier(0); /* rule 18: no MFMA hoist above wait */  \
    __builtin_amdgcn_s_setprio(1);                                              \
    acc[0][0] = __builtin_amdgcn_mfma_f32_32x32x16_bf16(a0_, b0_, acc[0][0], 0, 0, 0); \
    acc[0][1] = __builtin_amdgcn_mfma_f32_32x32x16_bf16(a0_, b1_, acc[0][1], 0, 0, 0); \
    acc[1][0] = __builtin_amdgcn_mfma_f32_32x32x16_bf16(a1_, b0_, acc[1][0], 0, 0, 0); \
    acc[1][1] = __builtin_amdgcn_mfma_f32_32x32x16_bf16(a1_, b1_, acc[1][1], 0, 0, 0); \
    acc[2][0] = __builtin_amdgcn_mfma_f32_32x32x16_bf16(a2_, b0_, acc[2][0], 0, 0, 0); \
    acc[2][1] = __builtin_amdgcn_mfma_f32_32x32x16_bf16(a2_, b1_, acc[2][1], 0, 0, 0); \
    acc[3][0] = __builtin_amdgcn_mfma_f32_32x32x16_bf16(a3_, b0_, acc[3][0], 0, 0, 0); \
    acc[3][1] = __builtin_amdgcn_mfma_f32_32x32x16_bf16(a3_, b1_, acc[3][1], 0, 0, 0); \
    __builtin_amdgcn_s_setprio(0);                                              \
    if ((VM) >= 0)                                                              \
        asm volatile("s_waitcnt vmcnt(%0)" :: "n"((VM) < 0 ? 0 : (VM)) : "memory"); \
    __builtin_amdgcn_s_barrier();                                               \
} while (0)

__global__ __launch_bounds__(512, 2) void gemm_kernel(const bf16* __restrict__ A,   // [BATCH][KDIM]
                                                      const bf16* __restrict__ Bt,  // [NDIM][KDIM]
                                                      const float* __restrict__ bias,
                                                      float* __restrict__ C) {      // [BATCH][NDIM]
    __shared__ __align__(16) bf16 lds[2 * 32768];  // 128 KiB

    const int tid  = threadIdx.x;
    const int lane = tid & 63;
    const int wv   = tid >> 6;
    const int rl   = lane & 31;
    const int kb   = lane >> 5;
    const int sx3  = rl & 3;  // read-side swizzle (4 chunks per 64B row)

    // T1: XCD swizzle, 768 blocks % 8 == 0 -> bijective.
    const int lid = blockIdx.y * gridDim.x + blockIdx.x;  // grid = (12, 64)
    const int sid = (lid & 7) * 96 + (lid >> 3);
    const long m0 = (long)(sid / 12) * 256;
    const long n0 = (long)(sid % 12) * 256;

    const int waveM = (wv >> 2) * 128;
    const int waveN = (wv & 3) * 64;

    // staging: thread t covers row t>>2 (+128 for 2nd call), source chunk
    // pre-swizzled sc = (t&3) ^ (row&3); dest linear (tid*16B per call).
    const int srow = tid >> 2;
    const int sc   = (tid & 3) ^ (srow & 3);
    const bf16* gA = A  + (m0 + srow) * KDIM + sc * 8;
    const bf16* gB = Bt + (n0 + srow) * KDIM + sc * 8;

    // fragment row bases (elem units; row stride 32 elems = 64B)
    const int aOff0 = (waveM + 0 * 32 + rl) * 32;
    const int aOff1 = (waveM + 1 * 32 + rl) * 32;
    const int aOff2 = (waveM + 2 * 32 + rl) * 32;
    const int aOff3 = (waveM + 3 * 32 + rl) * 32;
    const int bOff0 = 16384 + (waveN + 0 * 32 + rl) * 32;
    const int bOff1 = 16384 + (waveN + 1 * 32 + rl) * 32;

    f32x16 acc[4][2] = {};

    // prologue: stage all 4 units of tile 0 into buf 0; wait for kh0 only.
    STAGE_UNIT(0, 0, 0);  // A kh0
    STAGE_UNIT(0, 0, 1);  // B kh0
    STAGE_UNIT(0, 0, 2);  // A kh1
    STAGE_UNIT(0, 0, 3);  // B kh1
    asm volatile("s_waitcnt vmcnt(4)" ::: "memory");
    __builtin_amdgcn_s_barrier();

    const int NT = KDIM / 64;  // 48
#pragma unroll 2
    for (int t = 0; t < NT - 1; ++t) {
        const int p = t & 1;
        PHASE(0, p, 1, t + 1, -1);  // stage A-kh0(t+1)
        PHASE(1, p, 1, t + 1, 4);   // stage B-kh0(t+1); wait own kh1
        PHASE(2, p, 1, t + 1, -1);  // stage A-kh1(t+1)
        PHASE(3, p, 1, t + 1, 4);   // stage B-kh1(t+1); wait next kh0
    }
    // peeled last tile (p = 1): no staging; drain kh1 at ph1.
    PHASE(0, 1, 0, 0, -1);
    PHASE(1, 1, 0, 0, 0);
    PHASE(2, 1, 0, 0, -1);
    PHASE(3, 1, 0, 0, -1);

    // epilogue: C/D layout col=lane&31, row=(reg&3)+8*(reg>>2)+4*(lane>>5)
#pragma unroll
    for (int ni = 0; ni < 2; ++ni) {
        const long col = n0 + waveN + ni * 32 + rl;
        const float bv = bias[col];
#pragma unroll
        for (int mi = 0; mi < 4; ++mi) {
            const long rbase = m0 + waveM + mi * 32 + 4 * kb;
#pragma unroll
            for (int g = 0; g < 4; ++g)
#pragma unroll
                for (int t = 0; t < 4; ++t)
                    C[(rbase + 8 * g + t) * NDIM + col] = acc[mi][ni][4 * g + t] + bv;
        }
    }
}

// ---- fallback (only if ws_size too small): naive fp32 masked GEMM ----
__global__ __launch_bounds__(256) void naive_kernel(const float* __restrict__ x,
                                                    const float* __restrict__ w,
                                                    const float* __restrict__ bias,
                                                    const int* __restrict__ mask,
                                                    float* __restrict__ out) {
    const long idx = (long)blockIdx.x * 256 + threadIdx.x;
    const long bi = idx / NDIM;
    const int u = (int)(idx % NDIM);
    float s = 0.f;
    for (int k = 0; k < KDIM; k++)
        s += x[bi * KDIM + k] * w[(long)k * NDIM + u] * (float)mask[(long)u * KDIM + k];
    out[idx] = s + bias[u];
}

extern "C" void kernel_launch(void* const* d_in, const int* in_sizes, int n_in,
                              void* d_out, int out_size, void* d_ws, size_t ws_size,
                              hipStream_t stream) {
    const float* x    = (const float*)d_in[0];  // [16384, 3072] fp32
    const float* w    = (const float*)d_in[1];  // [3072, 3072] fp32
    const float* bias = (const float*)d_in[2];  // [3072] fp32
    const int*   mask = (const int*)d_in[3];    // [3072, 3072] int32
    float* out = (float*)d_out;                 // [16384, 3072] fp32

    const size_t needA = (size_t)BATCH * KDIM * sizeof(bf16);  // ~100.7 MB
    const size_t needW = (size_t)NDIM * KDIM * sizeof(bf16);   // ~18.9 MB

    if (ws_size < needA + needW) {
        const long total = (long)BATCH * NDIM;
        naive_kernel<<<(int)(total / 256), 256, 0, stream>>>(x, w, bias, mask, out);
        return;
    }

    bf16* Abf = (bf16*)d_ws;
    bf16* Wt  = (bf16*)((char*)d_ws + needA);

    cvt_a_kernel<<<(BATCH * (KDIM / 8)) / 256, 256, 0, stream>>>(x, Abf);
    weff_kernel<<<dim3(KDIM / 32, NDIM / 32), dim3(32, 8), 0, stream>>>(w, mask, Wt);
    gemm_kernel<<<dim3(NDIM / 256, BATCH / 256), 512, 0, stream>>>(Abf, Wt, bias, out);
}

// Round 4
// 610.153 us; speedup vs baseline: 1.1424x; 1.1217x over previous
//
#include <hip/hip_runtime.h>

#define BATCH 16384
#define KDIM  3072
#define NDIM  3072

typedef __bf16 bf16;
typedef bf16  bf16x8  __attribute__((ext_vector_type(8)));
typedef float f32x4   __attribute__((ext_vector_type(4)));

// async global->LDS, 16B per lane. HW dest = wave-uniform base + lane*16.
__device__ __forceinline__ void g2l16(const bf16* g, bf16* l) {
    __builtin_amdgcn_global_load_lds(
        (__attribute__((address_space(1))) unsigned int*)g,
        (__attribute__((address_space(3))) unsigned int*)l,
        16, 0, 0);
}

// ---- prep 1: fp32 inputs -> bf16, 8 elems/thread ----
__global__ __launch_bounds__(256) void cvt_a_kernel(const float* __restrict__ in,
                                                    bf16* __restrict__ out) {
    const long idx = (long)blockIdx.x * 256 + threadIdx.x;
    const float4* in4 = (const float4*)in;
    float4 a = in4[idx * 2];
    float4 b = in4[idx * 2 + 1];
    bf16x8 o;
    o[0] = (bf16)a.x; o[1] = (bf16)a.y; o[2] = (bf16)a.z; o[3] = (bf16)a.w;
    o[4] = (bf16)b.x; o[5] = (bf16)b.y; o[6] = (bf16)b.z; o[7] = (bf16)b.w;
    ((bf16x8*)out)[idx] = o;
}

// ---- prep 2: Weff_t[u][i] = bf16(w[i][u] * mask[u][i]) via LDS transpose ----
__global__ __launch_bounds__(256) void weff_kernel(const float* __restrict__ w,
                                                   const int* __restrict__ mask,
                                                   bf16* __restrict__ wt) {
    __shared__ float tile[32][33];
    const int i0 = blockIdx.x * 32;
    const int u0 = blockIdx.y * 32;
    const int tx = threadIdx.x, ty = threadIdx.y;
#pragma unroll
    for (int r = 0; r < 4; r++)
        tile[ty + 8 * r][tx] = w[(long)(i0 + ty + 8 * r) * NDIM + u0 + tx];
    __syncthreads();
#pragma unroll
    for (int r = 0; r < 4; r++) {
        int u = u0 + ty + 8 * r;
        int i = i0 + tx;
        float v = tile[tx][ty + 8 * r] * (float)mask[(long)u * KDIM + i];
        wt[(long)u * KDIM + i] = (bf16)v;
    }
}

// ---- main GEMM: faithful m201-template port ----
// 256x256 tile, BK=64, 8 waves. Wave output STRADDLES halves: M rows
// wm+{0..63} U 128+wm+{0..63} (wm=(wv>>2)*64), N cols wn+{0..31} U
// 128+wn+{0..31} (wn=(wv&3)*32). Phases are OUTPUT-QUADRANT-major
// (one C-quadrant x full K=64), so LDS halves staircase out of use:
//   A0 last ds_read p1, B1 p2, A1 p3, B0 p1 (B regs resident all tile).
// Stage 1 half-tile/phase (2 gloads): p1:B1(T+1) p2:A1(T+1) p3:A0(T+2)
// p4:B0(T+2); ONE vmcnt(4) per tile at p4 -> next tile fully covered,
// 2 half-tiles (4 loads) always in flight (T4). Slot-overwrite safety
// follows from the staircase; dbuf parity per tile.
// Swizzle (rule 21 both sides): rows 128B = 8 chunks; LDS[r][c] holds
// global chunk c^(r&7); read chunk gc^(r&7); bank group = gc^(l15&7),
// full 8-group spread.
__global__ __launch_bounds__(512, 2) void gemm_kernel(const bf16* __restrict__ A,   // [BATCH][KDIM]
                                                      const bf16* __restrict__ Bt,  // [NDIM][KDIM]
                                                      const float* __restrict__ bias,
                                                      float* __restrict__ C) {      // [BATCH][NDIM]
    __shared__ __align__(16) bf16 lds[2 * 32768];  // 128 KiB

    const int tid  = threadIdx.x;
    const int lane = tid & 63;
    const int wv   = tid >> 6;
    const int l15  = lane & 15;
    const int l4   = lane >> 4;        // 0..3
    const int sx   = l15 & 7;
    const int wm   = (wv >> 2) * 64;   // 0 or 64
    const int wn   = (wv & 3) * 32;    // 0,32,64,96

    // T1: XCD swizzle, 768 blocks % 8 == 0 -> bijective.
    const int lid = blockIdx.y * gridDim.x + blockIdx.x;  // grid = (12, 64)
    const int sid = (lid & 7) * 96 + (lid >> 3);
    const long m0 = (long)(sid / 12) * 256;
    const long n0 = (long)(sid % 12) * 256;

    // staging: thread t -> row t>>3 (+64 for 2nd call), chunk t&7, source
    // chunk pre-swizzled (t&7)^((t>>3)&7); dest linear tid*16B per call.
    const int srow = tid >> 3;
    const int gsc  = (tid & 7) ^ (srow & 7);
    const bf16* gAb = A  + (m0 + srow) * (long)KDIM + gsc * 8;
    const bf16* gBb = Bt + (n0 + srow) * (long)KDIM + gsc * 8;

#define STAGE_A(Q, KT, H) do {                                                  \
    const bf16* g_ = gAb + (long)((H) * 128) * KDIM + (long)(KT) * 64;          \
    bf16* d_ = &lds[(Q) * 32768 + (H) * 8192 + tid * 8];                        \
    g2l16(g_, d_);                                                              \
    g2l16(g_ + (long)64 * KDIM, d_ + 4096);                                     \
} while (0)
#define STAGE_B(Q, KT, H) do {                                                  \
    const bf16* g_ = gBb + (long)((H) * 128) * KDIM + (long)(KT) * 64;          \
    bf16* d_ = &lds[(Q) * 32768 + 16384 + (H) * 8192 + tid * 8];                \
    g2l16(g_, d_);                                                              \
    g2l16(g_ + (long)64 * KDIM, d_ + 4096);                                     \
} while (0)

    // fragment addressing (elem units; 64-elem = 128B rows, 8 chunks)
    const int aRow = (wm + l15) * 64;
    const int bRow = (wn + l15) * 64;
    const int cc0  = (l4 ^ sx) * 8;   // ks=0 chunk offset (swizzled)
    const int cc1  = cc0 ^ 32;        // ks=1: chunk^4 -> elems^32

    bf16x8 aF[4][2];   // current m-half A frags
    bf16x8 bF[4][2];   // all-tile-resident B frags (fn 0..3)
    f32x4  acc[8][4] = {};

#define RDA(BP, MH)                                                             \
    _Pragma("unroll") for (int f_ = 0; f_ < 4; ++f_) {                          \
        aF[f_][0] = *(const bf16x8*)((BP) + (MH) * 8192 + aRow + f_ * 1024 + cc0); \
        aF[f_][1] = *(const bf16x8*)((BP) + (MH) * 8192 + aRow + f_ * 1024 + cc1); \
    }
#define RDB(BP, NH)                                                             \
    _Pragma("unroll") for (int n_ = 0; n_ < 2; ++n_) {                          \
        bF[(NH) * 2 + n_][0] = *(const bf16x8*)((BP) + 16384 + (NH) * 8192 + bRow + n_ * 1024 + cc0); \
        bF[(NH) * 2 + n_][1] = *(const bf16x8*)((BP) + 16384 + (NH) * 8192 + bRow + n_ * 1024 + cc1); \
    }
#define MMQ(MH, NH)                                                             \
    _Pragma("unroll") for (int ks_ = 0; ks_ < 2; ++ks_)                         \
    _Pragma("unroll") for (int f_ = 0; f_ < 4; ++f_)                            \
    _Pragma("unroll") for (int n_ = 0; n_ < 2; ++n_)                            \
        acc[(MH) * 4 + f_][(NH) * 2 + n_] = __builtin_amdgcn_mfma_f32_16x16x32_bf16( \
            aF[f_][ks_], bF[(NH) * 2 + n_][ks_], acc[(MH) * 4 + f_][(NH) * 2 + n_], 0, 0, 0)

#define PHASE(P, MH, NH, READS, STAGE_STMT, DOVM) do {                          \
    asm volatile("" ::: "memory");                                              \
    const bf16* bp_ = &lds[(P) * 32768];                                        \
    READS;                                                                      \
    STAGE_STMT;                                                                 \
    asm volatile("" ::: "memory");                                              \
    __builtin_amdgcn_s_barrier();                                               \
    asm volatile("s_waitcnt lgkmcnt(0)" ::: "memory");                          \
    __builtin_amdgcn_sched_barrier(0);                                          \
    __builtin_amdgcn_s_setprio(1);                                              \
    MMQ(MH, NH);                                                                \
    __builtin_amdgcn_s_setprio(0);                                              \
    if (DOVM) asm volatile("s_waitcnt vmcnt(4)" ::: "memory");                  \
    __builtin_amdgcn_s_barrier();                                               \
} while (0)

#define RD_AB(MH, NH) RDA(bp_, MH); RDB(bp_, NH)
#define RD_ONLYB(NH)  RDB(bp_, NH)
#define RD_ONLYA(MH)  RDA(bp_, MH)
#define RD_NONE       ((void)0)

    // prologue: T0 all 4 halves + A0(T1),B0(T1); wait leaves T1's 4 loads.
    STAGE_A(0, 0, 0);  // A0(T0)
    STAGE_B(0, 0, 0);  // B0(T0)
    STAGE_B(0, 0, 1);  // B1(T0)
    STAGE_A(0, 0, 1);  // A1(T0)
    STAGE_A(1, 1, 0);  // A0(T1)
    STAGE_B(1, 1, 0);  // B0(T1)
    asm volatile("s_waitcnt vmcnt(4)" ::: "memory");
    __builtin_amdgcn_s_barrier();

    const int NT = KDIM / 64;  // 48 (even)
#pragma unroll 1
    for (int t = 0; t < NT; t += 2) {
        const int k1 = t + 1;                       // <= 47
        const int k2 = (t + 2 < NT) ? t + 2 : 0;    // wrap: dummy re-stage
        const int k3 = (t + 3 < NT) ? t + 3 : t + 3 - NT;
        // tile t (buf 0)
        PHASE(0, 0, 0, RD_AB(0, 0),  STAGE_B(1, k1, 1), 0);  // p1
        PHASE(0, 0, 1, RD_ONLYB(1),  STAGE_A(1, k1, 1), 0);  // p2
        PHASE(0, 1, 0, RD_ONLYA(1),  STAGE_A(0, k2, 0), 0);  // p3
        PHASE(0, 1, 1, RD_NONE,      STAGE_B(0, k2, 0), 1);  // p4 + vmcnt(4)
        // tile t+1 (buf 1)
        PHASE(1, 0, 0, RD_AB(0, 0),  STAGE_B(0, k2, 1), 0);  // p1
        PHASE(1, 0, 1, RD_ONLYB(1),  STAGE_A(0, k2, 1), 0);  // p2
        PHASE(1, 1, 0, RD_ONLYA(1),  STAGE_A(1, k3, 0), 0);  // p3
        PHASE(1, 1, 1, RD_NONE,      STAGE_B(1, k3, 0), 1);  // p4 + vmcnt(4)
    }
    asm volatile("s_waitcnt vmcnt(0)" ::: "memory");  // drain dummy stages

    // epilogue: 16x16x32 C/D layout col=lane&15, row=(lane>>4)*4+reg
    float bv[4];
#pragma unroll
    for (int n_ = 0; n_ < 4; ++n_) {
        const long gc = n0 + ((n_ < 2) ? (wn + n_ * 16) : (128 + wn + (n_ - 2) * 16)) + l15;
        bv[n_] = bias[gc];
    }
#pragma unroll
    for (int f_ = 0; f_ < 8; ++f_) {
        const long gm = m0 + ((f_ < 4) ? (wm + f_ * 16) : (128 + wm + (f_ - 4) * 16)) + l4 * 4;
#pragma unroll
        for (int n_ = 0; n_ < 4; ++n_) {
            const long gc = n0 + ((n_ < 2) ? (wn + n_ * 16) : (128 + wn + (n_ - 2) * 16)) + l15;
#pragma unroll
            for (int r_ = 0; r_ < 4; ++r_)
                C[(gm + r_) * NDIM + gc] = acc[f_][n_][r_] + bv[n_];
        }
    }
#undef STAGE_A
#undef STAGE_B
#undef RDA
#undef RDB
#undef MMQ
#undef PHASE
#undef RD_AB
#undef RD_ONLYB
#undef RD_ONLYA
#undef RD_NONE
}

// ---- fallback (only if ws_size too small): naive fp32 masked GEMM ----
__global__ __launch_bounds__(256) void naive_kernel(const float* __restrict__ x,
                                                    const float* __restrict__ w,
                                                    const float* __restrict__ bias,
                                                    const int* __restrict__ mask,
                                                    float* __restrict__ out) {
    const long idx = (long)blockIdx.x * 256 + threadIdx.x;
    const long bi = idx / NDIM;
    const int u = (int)(idx % NDIM);
    float s = 0.f;
    for (int k = 0; k < KDIM; k++)
        s += x[bi * KDIM + k] * w[(long)k * NDIM + u] * (float)mask[(long)u * KDIM + k];
    out[idx] = s + bias[u];
}

extern "C" void kernel_launch(void* const* d_in, const int* in_sizes, int n_in,
                              void* d_out, int out_size, void* d_ws, size_t ws_size,
                              hipStream_t stream) {
    const float* x    = (const float*)d_in[0];  // [16384, 3072] fp32
    const float* w    = (const float*)d_in[1];  // [3072, 3072] fp32
    const float* bias = (const float*)d_in[2];  // [3072] fp32
    const int*   mask = (const int*)d_in[3];    // [3072, 3072] int32
    float* out = (float*)d_out;                 // [16384, 3072] fp32

    const size_t needA = (size_t)BATCH * KDIM * sizeof(bf16);  // ~100.7 MB
    const size_t needW = (size_t)NDIM * KDIM * sizeof(bf16);   // ~18.9 MB

    if (ws_size < needA + needW) {
        const long total = (long)BATCH * NDIM;
        naive_kernel<<<(int)(total / 256), 256, 0, stream>>>(x, w, bias, mask, out);
        return;
    }

    bf16* Abf = (bf16*)d_ws;
    bf16* Wt  = (bf16*)((char*)d_ws + needA);

    cvt_a_kernel<<<(BATCH * (KDIM / 8)) / 256, 256, 0, stream>>>(x, Abf);
    weff_kernel<<<dim3(KDIM / 32, NDIM / 32), dim3(32, 8), 0, stream>>>(w, mask, Wt);
    gemm_kernel<<<dim3(NDIM / 256, BATCH / 256), 512, 0, stream>>>(Abf, Wt, bias, out);
}